// Round 1
// baseline (2985.274 us; speedup 1.0000x reference)
//
#include <hip/hip_runtime.h>

#define THREADS 256

// ---------------- degree / normalization ----------------

__global__ void k_deg_init(float* __restrict__ deg, int n) {
    int i = blockIdx.x * blockDim.x + threadIdx.x;
    if (i < n) deg[i] = 1.0f;   // self-loop contributes 1 to every node's degree
}

__global__ void k_deg_acc(const int* __restrict__ dst, float* __restrict__ deg, int E) {
    int i = blockIdx.x * blockDim.x + threadIdx.x;
    if (i < E) atomicAdd(&deg[dst[i]], 1.0f);
}

__global__ void k_rsqrt(float* __restrict__ deg, int n) {
    int i = blockIdx.x * blockDim.x + threadIdx.x;
    if (i < n) deg[i] = rsqrtf(deg[i]);   // deg >= 1 always (self-loops)
}

// ---------------- GEMM: out[n,128] = A[n,128] @ W[128,128] ----------------
// W staged in LDS (64 KB). 256 threads/block, 32 rows/block.

__global__ __launch_bounds__(256) void k_gemm128(const float* __restrict__ A,
                                                 const float* __restrict__ W,
                                                 float* __restrict__ out, int n) {
    __shared__ float Wl[128 * 128];
    for (int idx = threadIdx.x; idx < 128 * 128; idx += 256) Wl[idx] = W[idx];
    __syncthreads();
    const int j = threadIdx.x & 127;
    const int half = threadIdx.x >> 7;
    const int rowBase = blockIdx.x * 32;
    for (int r = half; r < 32; r += 2) {
        const int i = rowBase + r;
        if (i >= n) continue;
        const float4* a4 = (const float4*)(A + (size_t)i * 128);
        float acc = 0.f;
#pragma unroll
        for (int k4 = 0; k4 < 32; ++k4) {
            float4 av = a4[k4];
            const float* wr = &Wl[(k4 * 4) * 128 + j];
            acc += av.x * wr[0];
            acc += av.y * wr[128];
            acc += av.z * wr[256];
            acc += av.w * wr[384];
        }
        out[(size_t)i * 128 + j] = acc;
    }
}

// ---------------- final GEMM: [mu|lv] = A[n,128] @ [Wmu|Wlv] + [bmu|blv] ----
// writes directly into d_out, split layout (mu first N*64, then logvar)

__global__ __launch_bounds__(256) void k_gemm_out(const float* __restrict__ A,
                                                  const float* __restrict__ Wmu,
                                                  const float* __restrict__ Wlv,
                                                  const float* __restrict__ bmu,
                                                  const float* __restrict__ blv,
                                                  float* __restrict__ out, int n) {
    __shared__ float Wl[128 * 128];
    for (int idx = threadIdx.x; idx < 128 * 128; idx += 256) {
        int k = idx >> 7, j = idx & 127;
        Wl[idx] = (j < 64) ? Wmu[k * 64 + j] : Wlv[k * 64 + (j - 64)];
    }
    __syncthreads();
    const int j = threadIdx.x & 127;
    const int half = threadIdx.x >> 7;
    const float bias = (j < 64) ? bmu[j] : blv[j - 64];
    const int rowBase = blockIdx.x * 32;
    for (int r = half; r < 32; r += 2) {
        const int i = rowBase + r;
        if (i >= n) continue;
        const float4* a4 = (const float4*)(A + (size_t)i * 128);
        float acc = bias;
#pragma unroll
        for (int k4 = 0; k4 < 32; ++k4) {
            float4 av = a4[k4];
            const float* wr = &Wl[(k4 * 4) * 128 + j];
            acc += av.x * wr[0];
            acc += av.y * wr[128];
            acc += av.z * wr[256];
            acc += av.w * wr[384];
        }
        if (j < 64) out[(size_t)i * 64 + j] = acc;
        else        out[(size_t)n * 64 + (size_t)i * 64 + (j - 64)] = acc;
    }
}

// ---------------- self-loop / init kernels ----------------

// agg1[i][j] = b1[j] + h1[i][j] * dis[i]^2   (self-loop norm = 1/deg)
__global__ void k_selfloop1(const float* __restrict__ h, const float* __restrict__ b,
                            const float* __restrict__ dis, float* __restrict__ out, int n) {
    int t = blockIdx.x * blockDim.x + threadIdx.x;
    if (t >= n * 128) return;
    int i = t >> 7, j = t & 127;
    float d = dis[i];
    out[t] = b[j] + h[t] * d * d;
}

// agg2[i][j] = relu(agg1[i][j]) * dis[i]^2
__global__ void k_selfloop2(const float* __restrict__ agg1, const float* __restrict__ dis,
                            float* __restrict__ out, int n) {
    int t = blockIdx.x * blockDim.x + threadIdx.x;
    if (t >= n * 128) return;
    int i = t >> 7;
    float d = dis[i];
    out[t] = fmaxf(agg1[t], 0.f) * d * d;
}

// ---------------- edge scatter: out[dst] += (relu?)(h[src]) * dis[s]*dis[d] --
// 32 threads per edge, float4 gather, 4 f32 atomics per thread.

template <bool RELU>
__global__ void k_scatter(const float* __restrict__ h, const int* __restrict__ src,
                          const int* __restrict__ dst, const float* __restrict__ dis,
                          float* __restrict__ out, int E) {
    int t = blockIdx.x * blockDim.x + threadIdx.x;
    int e = t >> 5;
    if (e >= E) return;
    int c = t & 31;
    int s = src[e], d = dst[e];
    float w = dis[s] * dis[d];
    float4 v = *(const float4*)(h + (size_t)s * 128 + c * 4);
    if (RELU) {
        v.x = fmaxf(v.x, 0.f); v.y = fmaxf(v.y, 0.f);
        v.z = fmaxf(v.z, 0.f); v.w = fmaxf(v.w, 0.f);
    }
    float* o = out + (size_t)d * 128 + c * 4;
    atomicAdd(o + 0, v.x * w);
    atomicAdd(o + 1, v.y * w);
    atomicAdd(o + 2, v.z * w);
    atomicAdd(o + 3, v.w * w);
}

// ---------------- launch ----------------

extern "C" void kernel_launch(void* const* d_in, const int* in_sizes, int n_in,
                              void* d_out, int out_size, void* d_ws, size_t ws_size,
                              hipStream_t stream) {
    const float* x   = (const float*)d_in[0];
    const int*   ei  = (const int*)d_in[1];
    const float* W1  = (const float*)d_in[2];
    const float* b1  = (const float*)d_in[3];
    const float* Wmu = (const float*)d_in[4];
    const float* bmu = (const float*)d_in[5];
    const float* Wlv = (const float*)d_in[6];
    const float* blv = (const float*)d_in[7];
    float* out = (float*)d_out;

    const int n = in_sizes[0] / 128;   // 50000
    const int E = in_sizes[1] / 2;     // 800000
    const int* src = ei;
    const int* dst = ei + E;

    char* ws = (char*)d_ws;
    float* dis  = (float*)ws;                               // n floats
    float* h1   = (float*)(ws + (1 << 20));                 // n*128 floats
    float* agg1 = h1 + (size_t)n * 128;                     // n*128 floats
    float* agg2 = h1;                                       // reuse: h1 dead after scatter1

    const int gN    = (n + THREADS - 1) / THREADS;
    const int gE    = (E + THREADS - 1) / THREADS;
    const int gNF   = (n * 128 + THREADS - 1) / THREADS;
    const int gRows = (n + 31) / 32;
    const int gScat = ((E * 32) + THREADS - 1) / THREADS;

    // 1. degree -> dis
    k_deg_init<<<gN, THREADS, 0, stream>>>(dis, n);
    k_deg_acc<<<gE, THREADS, 0, stream>>>(dst, dis, E);
    k_rsqrt<<<gN, THREADS, 0, stream>>>(dis, n);

    // 2. h1 = x @ W1
    k_gemm128<<<gRows, THREADS, 0, stream>>>(x, W1, h1, n);

    // 3. agg1 = b1 + A_norm @ h1
    k_selfloop1<<<gNF, THREADS, 0, stream>>>(h1, b1, dis, agg1, n);
    k_scatter<false><<<gScat, THREADS, 0, stream>>>(h1, src, dst, dis, agg1, E);

    // 4. agg2 = A_norm @ relu(agg1)   (agg2 reuses h1's buffer)
    k_selfloop2<<<gNF, THREADS, 0, stream>>>(agg1, dis, agg2, n);
    k_scatter<true><<<gScat, THREADS, 0, stream>>>(agg1, src, dst, dis, agg2, E);

    // 5. [mu | logvar] = agg2 @ [Wmu|Wlv] + bias  -> d_out directly
    k_gemm_out<<<gRows, THREADS, 0, stream>>>(agg2, Wmu, Wlv, bmu, blv, out, n);
}

// Round 2
// 691.580 us; speedup vs baseline: 4.3166x; 4.3166x over previous
//
#include <hip/hip_runtime.h>

#define THREADS 256

// ================= CSR build =================

__global__ void k_zero(int* __restrict__ p, int n) {
    int i = blockIdx.x * blockDim.x + threadIdx.x;
    if (i < n) p[i] = 0;
}

__global__ void k_hist(const int* __restrict__ dst, int* __restrict__ count, int E) {
    int i = blockIdx.x * blockDim.x + threadIdx.x;
    if (i < E) atomicAdd(&count[dst[i]], 1);
}

// dis[i] = 1/sqrt(deg_i), deg_i = in-edges + 1 (self-loop)
__global__ void k_dis(const int* __restrict__ count, float* __restrict__ dis, int n) {
    int i = blockIdx.x * blockDim.x + threadIdx.x;
    if (i < n) dis[i] = rsqrtf((float)(count[i] + 1));
}

// single-block exclusive scan: rowptr/cursor from count
__global__ void k_scan(const int* __restrict__ count, int* __restrict__ rowptr,
                       int* __restrict__ cursor, int n) {
    __shared__ int tile[256];
    __shared__ int carry;
    if (threadIdx.x == 0) carry = 0;
    __syncthreads();
    int nt = (n + 255) / 256;
    for (int t = 0; t < nt; ++t) {
        int i = t * 256 + threadIdx.x;
        int v = (i < n) ? count[i] : 0;
        tile[threadIdx.x] = v;
        __syncthreads();
        for (int off = 1; off < 256; off <<= 1) {
            int add = (threadIdx.x >= off) ? tile[threadIdx.x - off] : 0;
            __syncthreads();
            tile[threadIdx.x] += add;
            __syncthreads();
        }
        int excl = carry + tile[threadIdx.x] - v;
        if (i < n) { rowptr[i] = excl; cursor[i] = excl; }
        __syncthreads();
        if (threadIdx.x == 255) carry += tile[255];
        __syncthreads();
    }
    if (threadIdx.x == 0) rowptr[n] = carry;
}

__global__ void k_fill(const int* __restrict__ src, const int* __restrict__ dst,
                       int* __restrict__ cursor, int* __restrict__ col, int E) {
    int e = blockIdx.x * blockDim.x + threadIdx.x;
    if (e >= E) return;
    int pos = atomicAdd(&cursor[dst[e]], 1);
    col[pos] = src[e];
}

// ================= GEMM: out[n,128] = A[n,128] @ W[128,128] =================

__global__ __launch_bounds__(256) void k_gemm128(const float* __restrict__ A,
                                                 const float* __restrict__ W,
                                                 float* __restrict__ out, int n) {
    __shared__ float Wl[128 * 128];
    for (int idx = threadIdx.x; idx < 128 * 128; idx += 256) Wl[idx] = W[idx];
    __syncthreads();
    const int j = threadIdx.x & 127;
    const int half = threadIdx.x >> 7;
    const int rowBase = blockIdx.x * 32;
    for (int r = half; r < 32; r += 2) {
        const int i = rowBase + r;
        if (i >= n) continue;
        const float4* a4 = (const float4*)(A + (size_t)i * 128);
        float acc = 0.f;
#pragma unroll
        for (int k4 = 0; k4 < 32; ++k4) {
            float4 av = a4[k4];
            const float* wr = &Wl[(k4 * 4) * 128 + j];
            acc += av.x * wr[0];
            acc += av.y * wr[128];
            acc += av.z * wr[256];
            acc += av.w * wr[384];
        }
        out[(size_t)i * 128 + j] = acc;
    }
}

// ======== final GEMM: [mu|lv] = A[n,128] @ [Wmu|Wlv] + bias -> d_out ========

__global__ __launch_bounds__(256) void k_gemm_out(const float* __restrict__ A,
                                                  const float* __restrict__ Wmu,
                                                  const float* __restrict__ Wlv,
                                                  const float* __restrict__ bmu,
                                                  const float* __restrict__ blv,
                                                  float* __restrict__ out, int n) {
    __shared__ float Wl[128 * 128];
    for (int idx = threadIdx.x; idx < 128 * 128; idx += 256) {
        int k = idx >> 7, j = idx & 127;
        Wl[idx] = (j < 64) ? Wmu[k * 64 + j] : Wlv[k * 64 + (j - 64)];
    }
    __syncthreads();
    const int j = threadIdx.x & 127;
    const int half = threadIdx.x >> 7;
    const float bias = (j < 64) ? bmu[j] : blv[j - 64];
    const int rowBase = blockIdx.x * 32;
    for (int r = half; r < 32; r += 2) {
        const int i = rowBase + r;
        if (i >= n) continue;
        const float4* a4 = (const float4*)(A + (size_t)i * 128);
        float acc = bias;
#pragma unroll
        for (int k4 = 0; k4 < 32; ++k4) {
            float4 av = a4[k4];
            const float* wr = &Wl[(k4 * 4) * 128 + j];
            acc += av.x * wr[0];
            acc += av.y * wr[128];
            acc += av.z * wr[256];
            acc += av.w * wr[384];
        }
        if (j < 64) out[(size_t)i * 64 + j] = acc;
        else        out[(size_t)n * 64 + (size_t)i * 64 + (j - 64)] = acc;
    }
}

// ================= gather-aggregate (no atomics) =================
// out[i][:] = (BIAS? b : 0) + relu?(h[i])*dis[i]^2 + sum_e relu?(h[src_e])*dis[src]*dis[i]
// one wave (64 lanes) per node; each lane owns 2 features (float2 = 8B/lane,
// a wave reads one contiguous 512B h-row per edge).

template <bool RELU, bool BIAS>
__global__ __launch_bounds__(256) void k_aggregate(const float* __restrict__ h,
                                                   const int* __restrict__ rowptr,
                                                   const int* __restrict__ col,
                                                   const float* __restrict__ dis,
                                                   const float* __restrict__ b,
                                                   float* __restrict__ out, int n) {
    int node = blockIdx.x * 4 + (threadIdx.x >> 6);
    if (node >= n) return;
    int lane = threadIdx.x & 63;
    float di = dis[node];

    float2 self = *(const float2*)(h + (size_t)node * 128 + lane * 2);
    if (RELU) { self.x = fmaxf(self.x, 0.f); self.y = fmaxf(self.y, 0.f); }
    float2 acc;
    acc.x = self.x * di * di;
    acc.y = self.y * di * di;
    if (BIAS) {
        float2 bb = *(const float2*)(b + lane * 2);
        acc.x += bb.x; acc.y += bb.y;
    }

    int beg = rowptr[node], end = rowptr[node + 1];
    for (int k = beg; k < end; ++k) {
        int s = col[k];
        float w = dis[s] * di;
        float2 v = *(const float2*)(h + (size_t)s * 128 + lane * 2);
        if (RELU) { v.x = fmaxf(v.x, 0.f); v.y = fmaxf(v.y, 0.f); }
        acc.x += v.x * w;
        acc.y += v.y * w;
    }
    *(float2*)(out + (size_t)node * 128 + lane * 2) = acc;
}

// ================= launch =================

extern "C" void kernel_launch(void* const* d_in, const int* in_sizes, int n_in,
                              void* d_out, int out_size, void* d_ws, size_t ws_size,
                              hipStream_t stream) {
    const float* x   = (const float*)d_in[0];
    const int*   ei  = (const int*)d_in[1];
    const float* W1  = (const float*)d_in[2];
    const float* b1  = (const float*)d_in[3];
    const float* Wmu = (const float*)d_in[4];
    const float* bmu = (const float*)d_in[5];
    const float* Wlv = (const float*)d_in[6];
    const float* blv = (const float*)d_in[7];
    float* out = (float*)d_out;

    const int n = in_sizes[0] / 128;   // 50000
    const int E = in_sizes[1] / 2;     // 800000
    const int* src = ei;
    const int* dst = ei + E;

    char* ws = (char*)d_ws;
    float* dis    = (float*)(ws + 0x00000);            // n floats      (<256KB)
    int*   count  = (int*)  (ws + 0x40000);            // n ints
    int*   rowptr = (int*)  (ws + 0x80000);            // n+1 ints
    int*   cursor = (int*)  (ws + 0xC0000);            // n ints
    int*   col    = (int*)  (ws + 0x100000);           // E ints (3.2MB)
    float* h1     = (float*)(ws + 0x500000);           // n*128 floats (25.6MB)
    float* agg1   = h1 + (size_t)n * 128;              // n*128 floats
    float* agg2   = h1;                                // reuse: h1 dead after pass 1

    const int gN    = (n + THREADS - 1) / THREADS;
    const int gE    = (E + THREADS - 1) / THREADS;
    const int gRows = (n + 31) / 32;
    const int gAgg  = (n + 3) / 4;

    // CSR build + degrees
    k_zero<<<gN, THREADS, 0, stream>>>(count, n);
    k_hist<<<gE, THREADS, 0, stream>>>(dst, count, E);
    k_dis <<<gN, THREADS, 0, stream>>>(count, dis, n);
    k_scan<<<1, THREADS, 0, stream>>>(count, rowptr, cursor, n);
    k_fill<<<gE, THREADS, 0, stream>>>(src, dst, cursor, col, E);

    // h1 = x @ W1
    k_gemm128<<<gRows, THREADS, 0, stream>>>(x, W1, h1, n);

    // agg1 = b1 + A_norm @ h1
    k_aggregate<false, true><<<gAgg, THREADS, 0, stream>>>(h1, rowptr, col, dis, b1, agg1, n);

    // agg2 = A_norm @ relu(agg1)
    k_aggregate<true, false><<<gAgg, THREADS, 0, stream>>>(agg1, rowptr, col, dis, nullptr, agg2, n);

    // [mu | logvar] = agg2 @ [Wmu|Wlv] + bias
    k_gemm_out<<<gRows, THREADS, 0, stream>>>(agg2, Wmu, Wlv, bmu, blv, out, n);
}

// Round 3
// 487.329 us; speedup vs baseline: 6.1258x; 1.4191x over previous
//
#include <hip/hip_runtime.h>

#define THREADS 256

// ================= CSR build =================

__global__ void k_zero(int* __restrict__ p, int n) {
    int i = blockIdx.x * blockDim.x + threadIdx.x;
    if (i < n) p[i] = 0;
}

__global__ void k_hist(const int* __restrict__ dst, int* __restrict__ count, int E) {
    int i = blockIdx.x * blockDim.x + threadIdx.x;
    if (i < E) atomicAdd(&count[dst[i]], 1);
}

// dis[i] = 1/sqrt(deg_i), deg_i = in-edges + 1 (self-loop)
__global__ void k_dis(const int* __restrict__ count, float* __restrict__ dis, int n) {
    int i = blockIdx.x * blockDim.x + threadIdx.x;
    if (i < n) dis[i] = rsqrtf((float)(count[i] + 1));
}

// ---- parallel exclusive scan, 3 stages ----
// A: per-block local exclusive scan (256 elems/block) + block sums
__global__ __launch_bounds__(256) void k_scan_local(const int* __restrict__ count,
                                                    int* __restrict__ excl,
                                                    int* __restrict__ bsum, int n) {
    __shared__ int tile[256];
    int i = blockIdx.x * 256 + threadIdx.x;
    int v = (i < n) ? count[i] : 0;
    tile[threadIdx.x] = v;
    __syncthreads();
    for (int off = 1; off < 256; off <<= 1) {
        int add = (threadIdx.x >= off) ? tile[threadIdx.x - off] : 0;
        __syncthreads();
        tile[threadIdx.x] += add;
        __syncthreads();
    }
    if (i < n) excl[i] = tile[threadIdx.x] - v;
    if (threadIdx.x == 255) bsum[blockIdx.x] = tile[255];
}

// B: single-block exclusive scan of the block sums (nb <= 256)
__global__ __launch_bounds__(256) void k_scan_bsum(int* __restrict__ bsum, int nb) {
    __shared__ int tile[256];
    int v = (threadIdx.x < nb) ? bsum[threadIdx.x] : 0;
    tile[threadIdx.x] = v;
    __syncthreads();
    for (int off = 1; off < 256; off <<= 1) {
        int add = (threadIdx.x >= off) ? tile[threadIdx.x - off] : 0;
        __syncthreads();
        tile[threadIdx.x] += add;
        __syncthreads();
    }
    if (threadIdx.x < nb) bsum[threadIdx.x] = tile[threadIdx.x] - v;
}

// C: add block offsets -> rowptr & cursor; rowptr[n] = E
__global__ void k_scan_add(const int* __restrict__ excl, const int* __restrict__ bsum,
                           int* __restrict__ rowptr, int* __restrict__ cursor,
                           int n, int E) {
    int i = blockIdx.x * blockDim.x + threadIdx.x;
    if (i < n) {
        int v = excl[i] + bsum[i >> 8];
        rowptr[i] = v;
        cursor[i] = v;
    }
    if (i == 0) rowptr[n] = E;
}

__global__ void k_fill(const int* __restrict__ src, const int* __restrict__ dst,
                       int* __restrict__ cursor, int* __restrict__ col, int E) {
    int e = blockIdx.x * blockDim.x + threadIdx.x;
    if (e >= E) return;
    int pos = atomicAdd(&cursor[dst[e]], 1);
    col[pos] = src[e];
}

// ================= GEMM: out[n,128] = A[n,128] @ W[128,128] =================

__global__ __launch_bounds__(256) void k_gemm128(const float* __restrict__ A,
                                                 const float* __restrict__ W,
                                                 float* __restrict__ out, int n) {
    __shared__ float Wl[128 * 128];
    for (int idx = threadIdx.x; idx < 128 * 128; idx += 256) Wl[idx] = W[idx];
    __syncthreads();
    const int j = threadIdx.x & 127;
    const int half = threadIdx.x >> 7;
    const int rowBase = blockIdx.x * 32;
    for (int r = half; r < 32; r += 2) {
        const int i = rowBase + r;
        if (i >= n) continue;
        const float4* a4 = (const float4*)(A + (size_t)i * 128);
        float acc = 0.f;
#pragma unroll
        for (int k4 = 0; k4 < 32; ++k4) {
            float4 av = a4[k4];
            const float* wr = &Wl[(k4 * 4) * 128 + j];
            acc += av.x * wr[0];
            acc += av.y * wr[128];
            acc += av.z * wr[256];
            acc += av.w * wr[384];
        }
        out[(size_t)i * 128 + j] = acc;
    }
}

// ======== final GEMM: [mu|lv] = A[n,128] @ [Wmu|Wlv] + bias -> d_out ========

__global__ __launch_bounds__(256) void k_gemm_out(const float* __restrict__ A,
                                                  const float* __restrict__ Wmu,
                                                  const float* __restrict__ Wlv,
                                                  const float* __restrict__ bmu,
                                                  const float* __restrict__ blv,
                                                  float* __restrict__ out, int n) {
    __shared__ float Wl[128 * 128];
    for (int idx = threadIdx.x; idx < 128 * 128; idx += 256) {
        int k = idx >> 7, j = idx & 127;
        Wl[idx] = (j < 64) ? Wmu[k * 64 + j] : Wlv[k * 64 + (j - 64)];
    }
    __syncthreads();
    const int j = threadIdx.x & 127;
    const int half = threadIdx.x >> 7;
    const float bias = (j < 64) ? bmu[j] : blv[j - 64];
    const int rowBase = blockIdx.x * 32;
    for (int r = half; r < 32; r += 2) {
        const int i = rowBase + r;
        if (i >= n) continue;
        const float4* a4 = (const float4*)(A + (size_t)i * 128);
        float acc = bias;
#pragma unroll
        for (int k4 = 0; k4 < 32; ++k4) {
            float4 av = a4[k4];
            const float* wr = &Wl[(k4 * 4) * 128 + j];
            acc += av.x * wr[0];
            acc += av.y * wr[128];
            acc += av.z * wr[256];
            acc += av.w * wr[384];
        }
        if (j < 64) out[(size_t)i * 64 + j] = acc;
        else        out[(size_t)n * 64 + (size_t)i * 64 + (j - 64)] = acc;
    }
}

// ================= gather-aggregate (no atomics) =================

template <bool RELU, bool BIAS>
__global__ __launch_bounds__(256) void k_aggregate(const float* __restrict__ h,
                                                   const int* __restrict__ rowptr,
                                                   const int* __restrict__ col,
                                                   const float* __restrict__ dis,
                                                   const float* __restrict__ b,
                                                   float* __restrict__ out, int n) {
    int node = blockIdx.x * 4 + (threadIdx.x >> 6);
    if (node >= n) return;
    int lane = threadIdx.x & 63;
    float di = dis[node];

    float2 self = *(const float2*)(h + (size_t)node * 128 + lane * 2);
    if (RELU) { self.x = fmaxf(self.x, 0.f); self.y = fmaxf(self.y, 0.f); }
    float2 acc;
    acc.x = self.x * di * di;
    acc.y = self.y * di * di;
    if (BIAS) {
        float2 bb = *(const float2*)(b + lane * 2);
        acc.x += bb.x; acc.y += bb.y;
    }

    int beg = rowptr[node], end = rowptr[node + 1];
    for (int k = beg; k < end; ++k) {
        int s = col[k];
        float w = dis[s] * di;
        float2 v = *(const float2*)(h + (size_t)s * 128 + lane * 2);
        if (RELU) { v.x = fmaxf(v.x, 0.f); v.y = fmaxf(v.y, 0.f); }
        acc.x += v.x * w;
        acc.y += v.y * w;
    }
    *(float2*)(out + (size_t)node * 128 + lane * 2) = acc;
}

// ================= launch =================

extern "C" void kernel_launch(void* const* d_in, const int* in_sizes, int n_in,
                              void* d_out, int out_size, void* d_ws, size_t ws_size,
                              hipStream_t stream) {
    const float* x   = (const float*)d_in[0];
    const int*   ei  = (const int*)d_in[1];
    const float* W1  = (const float*)d_in[2];
    const float* b1  = (const float*)d_in[3];
    const float* Wmu = (const float*)d_in[4];
    const float* bmu = (const float*)d_in[5];
    const float* Wlv = (const float*)d_in[6];
    const float* blv = (const float*)d_in[7];
    float* out = (float*)d_out;

    const int n = in_sizes[0] / 128;   // 50000
    const int E = in_sizes[1] / 2;     // 800000
    const int* src = ei;
    const int* dst = ei + E;

    char* ws = (char*)d_ws;
    float* dis    = (float*)(ws + 0x00000);            // n floats
    int*   count  = (int*)  (ws + 0x40000);            // n ints
    int*   rowptr = (int*)  (ws + 0x80000);            // n+1 ints
    int*   cursor = (int*)  (ws + 0xC0000);            // n ints
    int*   excl   = (int*)  (ws + 0x100000);           // n ints (scan temp)
    int*   bsum   = (int*)  (ws + 0x140000);           // <=256 ints
    int*   col    = (int*)  (ws + 0x180000);           // E ints (3.2MB)
    float* h1     = (float*)(ws + 0x580000);           // n*128 floats (25.6MB)
    float* agg1   = h1 + (size_t)n * 128;              // n*128 floats
    float* agg2   = h1;                                // reuse: h1 dead after pass 1

    const int gN    = (n + THREADS - 1) / THREADS;
    const int gE    = (E + THREADS - 1) / THREADS;
    const int gRows = (n + 31) / 32;
    const int gAgg  = (n + 3) / 4;
    const int nb    = (n + 255) / 256;                 // 196 <= 256

    // CSR build + degrees
    k_zero<<<gN, THREADS, 0, stream>>>(count, n);
    k_hist<<<gE, THREADS, 0, stream>>>(dst, count, E);
    k_dis <<<gN, THREADS, 0, stream>>>(count, dis, n);
    k_scan_local<<<nb, 256, 0, stream>>>(count, excl, bsum, n);
    k_scan_bsum <<<1, 256, 0, stream>>>(bsum, nb);
    k_scan_add  <<<gN, THREADS, 0, stream>>>(excl, bsum, rowptr, cursor, n, E);
    k_fill<<<gE, THREADS, 0, stream>>>(src, dst, cursor, col, E);

    // h1 = x @ W1
    k_gemm128<<<gRows, THREADS, 0, stream>>>(x, W1, h1, n);

    // agg1 = b1 + A_norm @ h1
    k_aggregate<false, true><<<gAgg, THREADS, 0, stream>>>(h1, rowptr, col, dis, b1, agg1, n);

    // agg2 = A_norm @ relu(agg1)
    k_aggregate<true, false><<<gAgg, THREADS, 0, stream>>>(agg1, rowptr, col, dis, nullptr, agg2, n);

    // [mu | logvar] = agg2 @ [Wmu|Wlv] + bias
    k_gemm_out<<<gRows, THREADS, 0, stream>>>(agg2, Wmu, Wlv, bmu, blv, out, n);
}

// Round 4
// 363.609 us; speedup vs baseline: 8.2101x; 1.3403x over previous
//
#include <hip/hip_runtime.h>

#define THREADS 256

// ================= CSR build =================

__global__ void k_zero(int* __restrict__ p, int n) {
    int i = blockIdx.x * blockDim.x + threadIdx.x;
    if (i < n) p[i] = 0;
}

__global__ void k_hist(const int* __restrict__ dst, int* __restrict__ count, int E) {
    int i = blockIdx.x * blockDim.x + threadIdx.x;
    if (i < E) atomicAdd(&count[dst[i]], 1);
}

// dis[i] = 1/sqrt(deg_i), deg_i = in-edges + 1 (self-loop)
__global__ void k_dis(const int* __restrict__ count, float* __restrict__ dis, int n) {
    int i = blockIdx.x * blockDim.x + threadIdx.x;
    if (i < n) dis[i] = rsqrtf((float)(count[i] + 1));
}

// ---- parallel exclusive scan, 3 stages ----
__global__ __launch_bounds__(256) void k_scan_local(const int* __restrict__ count,
                                                    int* __restrict__ excl,
                                                    int* __restrict__ bsum, int n) {
    __shared__ int tile[256];
    int i = blockIdx.x * 256 + threadIdx.x;
    int v = (i < n) ? count[i] : 0;
    tile[threadIdx.x] = v;
    __syncthreads();
    for (int off = 1; off < 256; off <<= 1) {
        int add = (threadIdx.x >= off) ? tile[threadIdx.x - off] : 0;
        __syncthreads();
        tile[threadIdx.x] += add;
        __syncthreads();
    }
    if (i < n) excl[i] = tile[threadIdx.x] - v;
    if (threadIdx.x == 255) bsum[blockIdx.x] = tile[255];
}

__global__ __launch_bounds__(256) void k_scan_bsum(int* __restrict__ bsum, int nb) {
    __shared__ int tile[256];
    int v = (threadIdx.x < nb) ? bsum[threadIdx.x] : 0;
    tile[threadIdx.x] = v;
    __syncthreads();
    for (int off = 1; off < 256; off <<= 1) {
        int add = (threadIdx.x >= off) ? tile[threadIdx.x - off] : 0;
        __syncthreads();
        tile[threadIdx.x] += add;
        __syncthreads();
    }
    if (threadIdx.x < nb) bsum[threadIdx.x] = tile[threadIdx.x] - v;
}

__global__ void k_scan_add(const int* __restrict__ excl, const int* __restrict__ bsum,
                           int* __restrict__ rowptr, int* __restrict__ cursor,
                           int n, int E) {
    int i = blockIdx.x * blockDim.x + threadIdx.x;
    if (i < n) {
        int v = excl[i] + bsum[i >> 8];
        rowptr[i] = v;
        cursor[i] = v;
    }
    if (i == 0) rowptr[n] = E;
}

__global__ void k_fill(const int* __restrict__ src, const int* __restrict__ dst,
                       int* __restrict__ cursor, int* __restrict__ col, int E) {
    int e = blockIdx.x * blockDim.x + threadIdx.x;
    if (e >= E) return;
    int pos = atomicAdd(&cursor[dst[e]], 1);
    col[pos] = src[e];
}

// ========== register-tiled GEMM: out[n,128] = A[n,128] @ W[128,128] =========
// 256 thr/block = 16 row-groups x 16 col-groups; thread tile 4 rows x 8 cols.
// Per k-quad: 4 global dwordx4 (A, L1-broadcast) + 8 ds_read_b128 (W) + 128 FMA.

__global__ __launch_bounds__(256) void k_gemm128_rt(const float* __restrict__ A,
                                                    const float* __restrict__ W,
                                                    float* __restrict__ out, int n) {
    __shared__ float Wl[128 * 128];
    for (int idx = threadIdx.x * 4; idx < 128 * 128; idx += 256 * 4)
        *(float4*)&Wl[idx] = *(const float4*)&W[idx];
    __syncthreads();

    const int cg = threadIdx.x & 15;
    const int rg = threadIdx.x >> 4;
    const int j0 = cg * 8;
    const int r0 = blockIdx.x * 64 + rg * 4;

    int ri[4];
#pragma unroll
    for (int r = 0; r < 4; ++r) { int i = r0 + r; ri[r] = (i < n) ? i : (n - 1); }

    float acc[4][8];
#pragma unroll
    for (int r = 0; r < 4; ++r)
#pragma unroll
        for (int c = 0; c < 8; ++c) acc[r][c] = 0.f;

#pragma unroll 4
    for (int k4 = 0; k4 < 32; ++k4) {
        float4 a[4];
#pragma unroll
        for (int r = 0; r < 4; ++r)
            a[r] = *(const float4*)(A + (size_t)ri[r] * 128 + k4 * 4);
#pragma unroll
        for (int kk = 0; kk < 4; ++kk) {
            float4 w0 = *(const float4*)&Wl[(k4 * 4 + kk) * 128 + j0];
            float4 w1 = *(const float4*)&Wl[(k4 * 4 + kk) * 128 + j0 + 4];
#pragma unroll
            for (int r = 0; r < 4; ++r) {
                float av = (kk == 0) ? a[r].x : (kk == 1) ? a[r].y : (kk == 2) ? a[r].z : a[r].w;
                acc[r][0] += av * w0.x; acc[r][1] += av * w0.y;
                acc[r][2] += av * w0.z; acc[r][3] += av * w0.w;
                acc[r][4] += av * w1.x; acc[r][5] += av * w1.y;
                acc[r][6] += av * w1.z; acc[r][7] += av * w1.w;
            }
        }
    }

#pragma unroll
    for (int r = 0; r < 4; ++r) {
        int i = r0 + r;
        if (i >= n) continue;
        float4 o0 = {acc[r][0], acc[r][1], acc[r][2], acc[r][3]};
        float4 o1 = {acc[r][4], acc[r][5], acc[r][6], acc[r][7]};
        *(float4*)(out + (size_t)i * 128 + j0)     = o0;
        *(float4*)(out + (size_t)i * 128 + j0 + 4) = o1;
    }
}

// ==== register-tiled final GEMM: [mu|lv] = A @ [Wmu|Wlv] + bias -> d_out ====

__global__ __launch_bounds__(256) void k_gemm_out_rt(const float* __restrict__ A,
                                                     const float* __restrict__ Wmu,
                                                     const float* __restrict__ Wlv,
                                                     const float* __restrict__ bmu,
                                                     const float* __restrict__ blv,
                                                     float* __restrict__ out, int n) {
    __shared__ float Wl[128 * 128];
    for (int idx = threadIdx.x * 4; idx < 128 * 128; idx += 256 * 4) {
        int k = idx >> 7, j = idx & 127;
        float4 v = (j < 64) ? *(const float4*)&Wmu[k * 64 + j]
                            : *(const float4*)&Wlv[k * 64 + (j - 64)];
        *(float4*)&Wl[idx] = v;
    }
    __syncthreads();

    const int cg = threadIdx.x & 15;
    const int rg = threadIdx.x >> 4;
    const int j0 = cg * 8;
    const int r0 = blockIdx.x * 64 + rg * 4;

    float bb[8];
#pragma unroll
    for (int c = 0; c < 8; ++c) {
        int j = j0 + c;
        bb[c] = (j < 64) ? bmu[j] : blv[j - 64];
    }

    int ri[4];
#pragma unroll
    for (int r = 0; r < 4; ++r) { int i = r0 + r; ri[r] = (i < n) ? i : (n - 1); }

    float acc[4][8];
#pragma unroll
    for (int r = 0; r < 4; ++r)
#pragma unroll
        for (int c = 0; c < 8; ++c) acc[r][c] = bb[c];

#pragma unroll 4
    for (int k4 = 0; k4 < 32; ++k4) {
        float4 a[4];
#pragma unroll
        for (int r = 0; r < 4; ++r)
            a[r] = *(const float4*)(A + (size_t)ri[r] * 128 + k4 * 4);
#pragma unroll
        for (int kk = 0; kk < 4; ++kk) {
            float4 w0 = *(const float4*)&Wl[(k4 * 4 + kk) * 128 + j0];
            float4 w1 = *(const float4*)&Wl[(k4 * 4 + kk) * 128 + j0 + 4];
#pragma unroll
            for (int r = 0; r < 4; ++r) {
                float av = (kk == 0) ? a[r].x : (kk == 1) ? a[r].y : (kk == 2) ? a[r].z : a[r].w;
                acc[r][0] += av * w0.x; acc[r][1] += av * w0.y;
                acc[r][2] += av * w0.z; acc[r][3] += av * w0.w;
                acc[r][4] += av * w1.x; acc[r][5] += av * w1.y;
                acc[r][6] += av * w1.z; acc[r][7] += av * w1.w;
            }
        }
    }

#pragma unroll
    for (int r = 0; r < 4; ++r) {
        int i = r0 + r;
        if (i >= n) continue;
        float4 o0 = {acc[r][0], acc[r][1], acc[r][2], acc[r][3]};
        float4 o1 = {acc[r][4], acc[r][5], acc[r][6], acc[r][7]};
        if (j0 < 64) {
            *(float4*)(out + (size_t)i * 64 + j0)     = o0;
            *(float4*)(out + (size_t)i * 64 + j0 + 4) = o1;
        } else {
            float* lv = out + (size_t)n * 64;
            *(float4*)(lv + (size_t)i * 64 + (j0 - 64))     = o0;
            *(float4*)(lv + (size_t)i * 64 + (j0 - 64) + 4) = o1;
        }
    }
}

// ================= gather-aggregate (no atomics) =================

template <bool RELU, bool BIAS>
__global__ __launch_bounds__(256) void k_aggregate(const float* __restrict__ h,
                                                   const int* __restrict__ rowptr,
                                                   const int* __restrict__ col,
                                                   const float* __restrict__ dis,
                                                   const float* __restrict__ b,
                                                   float* __restrict__ out, int n) {
    int node = blockIdx.x * 4 + (threadIdx.x >> 6);
    if (node >= n) return;
    int lane = threadIdx.x & 63;
    float di = dis[node];

    float2 self = *(const float2*)(h + (size_t)node * 128 + lane * 2);
    if (RELU) { self.x = fmaxf(self.x, 0.f); self.y = fmaxf(self.y, 0.f); }
    float2 acc;
    acc.x = self.x * di * di;
    acc.y = self.y * di * di;
    if (BIAS) {
        float2 bb = *(const float2*)(b + lane * 2);
        acc.x += bb.x; acc.y += bb.y;
    }

    int beg = rowptr[node], end = rowptr[node + 1];
    for (int k = beg; k < end; ++k) {
        int s = col[k];
        float w = dis[s] * di;
        float2 v = *(const float2*)(h + (size_t)s * 128 + lane * 2);
        if (RELU) { v.x = fmaxf(v.x, 0.f); v.y = fmaxf(v.y, 0.f); }
        acc.x += v.x * w;
        acc.y += v.y * w;
    }
    *(float2*)(out + (size_t)node * 128 + lane * 2) = acc;
}

// ================= launch =================

extern "C" void kernel_launch(void* const* d_in, const int* in_sizes, int n_in,
                              void* d_out, int out_size, void* d_ws, size_t ws_size,
                              hipStream_t stream) {
    const float* x   = (const float*)d_in[0];
    const int*   ei  = (const int*)d_in[1];
    const float* W1  = (const float*)d_in[2];
    const float* b1  = (const float*)d_in[3];
    const float* Wmu = (const float*)d_in[4];
    const float* bmu = (const float*)d_in[5];
    const float* Wlv = (const float*)d_in[6];
    const float* blv = (const float*)d_in[7];
    float* out = (float*)d_out;

    const int n = in_sizes[0] / 128;   // 50000
    const int E = in_sizes[1] / 2;     // 800000
    const int* src = ei;
    const int* dst = ei + E;

    char* ws = (char*)d_ws;
    float* dis    = (float*)(ws + 0x00000);
    int*   count  = (int*)  (ws + 0x40000);
    int*   rowptr = (int*)  (ws + 0x80000);
    int*   cursor = (int*)  (ws + 0xC0000);
    int*   excl   = (int*)  (ws + 0x100000);
    int*   bsum   = (int*)  (ws + 0x140000);
    int*   col    = (int*)  (ws + 0x180000);
    float* h1     = (float*)(ws + 0x580000);
    float* agg1   = h1 + (size_t)n * 128;
    float* agg2   = h1;

    const int gN    = (n + THREADS - 1) / THREADS;
    const int gE    = (E + THREADS - 1) / THREADS;
    const int gAgg  = (n + 3) / 4;
    const int gGemm = (n + 63) / 64;
    const int nb    = (n + 255) / 256;

    // CSR build + degrees
    k_zero<<<gN, THREADS, 0, stream>>>(count, n);
    k_hist<<<gE, THREADS, 0, stream>>>(dst, count, E);
    k_dis <<<gN, THREADS, 0, stream>>>(count, dis, n);
    k_scan_local<<<nb, 256, 0, stream>>>(count, excl, bsum, n);
    k_scan_bsum <<<1, 256, 0, stream>>>(bsum, nb);
    k_scan_add  <<<gN, THREADS, 0, stream>>>(excl, bsum, rowptr, cursor, n, E);
    k_fill<<<gE, THREADS, 0, stream>>>(src, dst, cursor, col, E);

    // h1 = x @ W1
    k_gemm128_rt<<<gGemm, THREADS, 0, stream>>>(x, W1, h1, n);

    // agg1 = b1 + A_norm @ h1
    k_aggregate<false, true><<<gAgg, THREADS, 0, stream>>>(h1, rowptr, col, dis, b1, agg1, n);

    // agg2 = A_norm @ relu(agg1)
    k_aggregate<true, false><<<gAgg, THREADS, 0, stream>>>(agg1, rowptr, col, dis, nullptr, agg2, n);

    // [mu | logvar] = agg2 @ [Wmu|Wlv] + bias
    k_gemm_out_rt<<<gGemm, THREADS, 0, stream>>>(agg2, Wmu, Wlv, bmu, blv, out, n);
}

// Round 5
// 256.593 us; speedup vs baseline: 11.6343x; 1.4171x over previous
//
#include <hip/hip_runtime.h>
#include <hip/hip_bf16.h>

#define THREADS 256

// ---------- bf16 pack/unpack helpers ----------
__device__ __forceinline__ unsigned pack2(float a, float b) {
    __hip_bfloat16 ba = __float2bfloat16(a);
    __hip_bfloat16 bb = __float2bfloat16(b);
    unsigned short ua, ub;
    __builtin_memcpy(&ua, &ba, 2);
    __builtin_memcpy(&ub, &bb, 2);
    return ((unsigned)ub << 16) | ua;
}
__device__ __forceinline__ float unpack_lo(unsigned u) { return __uint_as_float(u << 16); }
__device__ __forceinline__ float unpack_hi(unsigned u) { return __uint_as_float(u & 0xffff0000u); }

// ================= CSR build =================

__global__ void k_zero(int* __restrict__ p, int n) {
    int i = blockIdx.x * blockDim.x + threadIdx.x;
    if (i < n) p[i] = 0;
}

__global__ void k_hist(const int* __restrict__ dst, int* __restrict__ count, int E) {
    int i = blockIdx.x * blockDim.x + threadIdx.x;
    if (i < E) atomicAdd(&count[dst[i]], 1);
}

__global__ void k_dis(const int* __restrict__ count, float* __restrict__ dis, int n) {
    int i = blockIdx.x * blockDim.x + threadIdx.x;
    if (i < n) dis[i] = rsqrtf((float)(count[i] + 1));
}

__global__ __launch_bounds__(256) void k_scan_local(const int* __restrict__ count,
                                                    int* __restrict__ excl,
                                                    int* __restrict__ bsum, int n) {
    __shared__ int tile[256];
    int i = blockIdx.x * 256 + threadIdx.x;
    int v = (i < n) ? count[i] : 0;
    tile[threadIdx.x] = v;
    __syncthreads();
    for (int off = 1; off < 256; off <<= 1) {
        int add = (threadIdx.x >= off) ? tile[threadIdx.x - off] : 0;
        __syncthreads();
        tile[threadIdx.x] += add;
        __syncthreads();
    }
    if (i < n) excl[i] = tile[threadIdx.x] - v;
    if (threadIdx.x == 255) bsum[blockIdx.x] = tile[255];
}

__global__ __launch_bounds__(256) void k_scan_bsum(int* __restrict__ bsum, int nb) {
    __shared__ int tile[256];
    int v = (threadIdx.x < nb) ? bsum[threadIdx.x] : 0;
    tile[threadIdx.x] = v;
    __syncthreads();
    for (int off = 1; off < 256; off <<= 1) {
        int add = (threadIdx.x >= off) ? tile[threadIdx.x - off] : 0;
        __syncthreads();
        tile[threadIdx.x] += add;
        __syncthreads();
    }
    if (threadIdx.x < nb) bsum[threadIdx.x] = tile[threadIdx.x] - v;
}

__global__ void k_scan_add(const int* __restrict__ excl, const int* __restrict__ bsum,
                           int* __restrict__ rowptr, int* __restrict__ cursor,
                           int n, int E) {
    int i = blockIdx.x * blockDim.x + threadIdx.x;
    if (i < n) {
        int v = excl[i] + bsum[i >> 8];
        rowptr[i] = v;
        cursor[i] = v;
    }
    if (i == 0) rowptr[n] = E;
}

__global__ void k_fill(const int* __restrict__ src, const int* __restrict__ dst,
                       int* __restrict__ cursor, int* __restrict__ col, int E) {
    int e = blockIdx.x * blockDim.x + threadIdx.x;
    if (e >= E) return;
    int pos = atomicAdd(&cursor[dst[e]], 1);
    col[pos] = src[e];
}

// ========== register-tiled GEMM: hb[n,128](bf16) = A[n,128] @ W[128,128] ====
// 16 row-groups x 16 col-groups; thread tile 4 rows x 8 cols; bf16 packed out.

__global__ __launch_bounds__(256) void k_gemm128_rt(const float* __restrict__ A,
                                                    const float* __restrict__ W,
                                                    uint4* __restrict__ outb, int n) {
    __shared__ float Wl[128 * 128];
    for (int idx = threadIdx.x * 4; idx < 128 * 128; idx += 256 * 4)
        *(float4*)&Wl[idx] = *(const float4*)&W[idx];
    __syncthreads();

    const int cg = threadIdx.x & 15;
    const int rg = threadIdx.x >> 4;
    const int j0 = cg * 8;
    const int r0 = blockIdx.x * 64 + rg * 4;

    int ri[4];
#pragma unroll
    for (int r = 0; r < 4; ++r) { int i = r0 + r; ri[r] = (i < n) ? i : (n - 1); }

    float acc[4][8];
#pragma unroll
    for (int r = 0; r < 4; ++r)
#pragma unroll
        for (int c = 0; c < 8; ++c) acc[r][c] = 0.f;

#pragma unroll 4
    for (int k4 = 0; k4 < 32; ++k4) {
        float4 a[4];
#pragma unroll
        for (int r = 0; r < 4; ++r)
            a[r] = *(const float4*)(A + (size_t)ri[r] * 128 + k4 * 4);
#pragma unroll
        for (int kk = 0; kk < 4; ++kk) {
            float4 w0 = *(const float4*)&Wl[(k4 * 4 + kk) * 128 + j0];
            float4 w1 = *(const float4*)&Wl[(k4 * 4 + kk) * 128 + j0 + 4];
#pragma unroll
            for (int r = 0; r < 4; ++r) {
                float av = (kk == 0) ? a[r].x : (kk == 1) ? a[r].y : (kk == 2) ? a[r].z : a[r].w;
                acc[r][0] += av * w0.x; acc[r][1] += av * w0.y;
                acc[r][2] += av * w0.z; acc[r][3] += av * w0.w;
                acc[r][4] += av * w1.x; acc[r][5] += av * w1.y;
                acc[r][6] += av * w1.z; acc[r][7] += av * w1.w;
            }
        }
    }

#pragma unroll
    for (int r = 0; r < 4; ++r) {
        int i = r0 + r;
        if (i >= n) continue;
        uint4 o;
        o.x = pack2(acc[r][0], acc[r][1]);
        o.y = pack2(acc[r][2], acc[r][3]);
        o.z = pack2(acc[r][4], acc[r][5]);
        o.w = pack2(acc[r][6], acc[r][7]);
        outb[(size_t)i * 16 + cg] = o;
    }
}

// ==== register-tiled final GEMM: [mu|lv] = A @ [Wmu|Wlv] + bias -> d_out ====

__global__ __launch_bounds__(256) void k_gemm_out_rt(const float* __restrict__ A,
                                                     const float* __restrict__ Wmu,
                                                     const float* __restrict__ Wlv,
                                                     const float* __restrict__ bmu,
                                                     const float* __restrict__ blv,
                                                     float* __restrict__ out, int n) {
    __shared__ float Wl[128 * 128];
    for (int idx = threadIdx.x * 4; idx < 128 * 128; idx += 256 * 4) {
        int k = idx >> 7, j = idx & 127;
        float4 v = (j < 64) ? *(const float4*)&Wmu[k * 64 + j]
                            : *(const float4*)&Wlv[k * 64 + (j - 64)];
        *(float4*)&Wl[idx] = v;
    }
    __syncthreads();

    const int cg = threadIdx.x & 15;
    const int rg = threadIdx.x >> 4;
    const int j0 = cg * 8;
    const int r0 = blockIdx.x * 64 + rg * 4;

    float bb[8];
#pragma unroll
    for (int c = 0; c < 8; ++c) {
        int j = j0 + c;
        bb[c] = (j < 64) ? bmu[j] : blv[j - 64];
    }

    int ri[4];
#pragma unroll
    for (int r = 0; r < 4; ++r) { int i = r0 + r; ri[r] = (i < n) ? i : (n - 1); }

    float acc[4][8];
#pragma unroll
    for (int r = 0; r < 4; ++r)
#pragma unroll
        for (int c = 0; c < 8; ++c) acc[r][c] = bb[c];

#pragma unroll 4
    for (int k4 = 0; k4 < 32; ++k4) {
        float4 a[4];
#pragma unroll
        for (int r = 0; r < 4; ++r)
            a[r] = *(const float4*)(A + (size_t)ri[r] * 128 + k4 * 4);
#pragma unroll
        for (int kk = 0; kk < 4; ++kk) {
            float4 w0 = *(const float4*)&Wl[(k4 * 4 + kk) * 128 + j0];
            float4 w1 = *(const float4*)&Wl[(k4 * 4 + kk) * 128 + j0 + 4];
#pragma unroll
            for (int r = 0; r < 4; ++r) {
                float av = (kk == 0) ? a[r].x : (kk == 1) ? a[r].y : (kk == 2) ? a[r].z : a[r].w;
                acc[r][0] += av * w0.x; acc[r][1] += av * w0.y;
                acc[r][2] += av * w0.z; acc[r][3] += av * w0.w;
                acc[r][4] += av * w1.x; acc[r][5] += av * w1.y;
                acc[r][6] += av * w1.z; acc[r][7] += av * w1.w;
            }
        }
    }

#pragma unroll
    for (int r = 0; r < 4; ++r) {
        int i = r0 + r;
        if (i >= n) continue;
        float4 o0 = {acc[r][0], acc[r][1], acc[r][2], acc[r][3]};
        float4 o1 = {acc[r][4], acc[r][5], acc[r][6], acc[r][7]};
        if (j0 < 64) {
            *(float4*)(out + (size_t)i * 64 + j0)     = o0;
            *(float4*)(out + (size_t)i * 64 + j0 + 4) = o1;
        } else {
            float* lv = out + (size_t)n * 64;
            *(float4*)(lv + (size_t)i * 64 + (j0 - 64))     = o0;
            *(float4*)(lv + (size_t)i * 64 + (j0 - 64) + 4) = o1;
        }
    }
}

// ================= bf16 gather-aggregate =================
// One 64-lane wave per node, quarter-wave (16 lanes x 16B) per edge:
// 4 edges in flight + 1-deep prefetch. Combine quarters via shfl_xor(16,32).
// PASS1: out = bf16(relu(bias + self*di^2 + sum))   (relu folded into store)
// PASS2: out = f32 (self*di^2 + sum), gather source already relu'd

template <bool PASS2>
__global__ __launch_bounds__(256) void k_agg_bf16(const uint4* __restrict__ hb,
                                                  const int* __restrict__ rowptr,
                                                  const int* __restrict__ col,
                                                  const float* __restrict__ dis,
                                                  const float* __restrict__ bias,
                                                  uint4* __restrict__ outb,
                                                  float* __restrict__ outf, int n) {
    int node = blockIdx.x * 4 + (threadIdx.x >> 6);
    if (node >= n) return;
    int lane = threadIdx.x & 63;
    int q = lane >> 4, l = lane & 15;
    float di = dis[node];

    float acc[8];
#pragma unroll
    for (int c = 0; c < 8; ++c) acc[c] = 0.f;

    int end = rowptr[node + 1];
    int k = rowptr[node] + q;

    int s0 = (k < end) ? col[k] : -1;
    uint4 v0 = {0, 0, 0, 0};
    float w0 = 0.f;
    if (s0 >= 0) { v0 = hb[(size_t)s0 * 16 + l]; w0 = dis[s0] * di; }

    while (k < end) {
        int k1 = k + 4;
        int s1 = (k1 < end) ? col[k1] : -1;
        uint4 v1 = {0, 0, 0, 0};
        float w1 = 0.f;
        if (s1 >= 0) { v1 = hb[(size_t)s1 * 16 + l]; w1 = dis[s1] * di; }

        acc[0] += unpack_lo(v0.x) * w0; acc[1] += unpack_hi(v0.x) * w0;
        acc[2] += unpack_lo(v0.y) * w0; acc[3] += unpack_hi(v0.y) * w0;
        acc[4] += unpack_lo(v0.z) * w0; acc[5] += unpack_hi(v0.z) * w0;
        acc[6] += unpack_lo(v0.w) * w0; acc[7] += unpack_hi(v0.w) * w0;

        k = k1; s0 = s1; v0 = v1; w0 = w1;
    }

#pragma unroll
    for (int c = 0; c < 8; ++c) acc[c] += __shfl_xor(acc[c], 16);
#pragma unroll
    for (int c = 0; c < 8; ++c) acc[c] += __shfl_xor(acc[c], 32);

    if (q == 0) {
        uint4 sv = hb[(size_t)node * 16 + l];
        float d2 = di * di;
        float self[8];
        self[0] = unpack_lo(sv.x); self[1] = unpack_hi(sv.x);
        self[2] = unpack_lo(sv.y); self[3] = unpack_hi(sv.y);
        self[4] = unpack_lo(sv.z); self[5] = unpack_hi(sv.z);
        self[6] = unpack_lo(sv.w); self[7] = unpack_hi(sv.w);
        if (!PASS2) {
            float4 b0 = *(const float4*)(bias + l * 8);
            float4 b1 = *(const float4*)(bias + l * 8 + 4);
            float bv[8] = {b0.x, b0.y, b0.z, b0.w, b1.x, b1.y, b1.z, b1.w};
#pragma unroll
            for (int c = 0; c < 8; ++c)
                acc[c] = fmaxf(acc[c] + self[c] * d2 + bv[c], 0.f);
            uint4 o;
            o.x = pack2(acc[0], acc[1]);
            o.y = pack2(acc[2], acc[3]);
            o.z = pack2(acc[4], acc[5]);
            o.w = pack2(acc[6], acc[7]);
            outb[(size_t)node * 16 + l] = o;
        } else {
#pragma unroll
            for (int c = 0; c < 8; ++c) acc[c] += self[c] * d2;
            float4 o0 = {acc[0], acc[1], acc[2], acc[3]};
            float4 o1 = {acc[4], acc[5], acc[6], acc[7]};
            *(float4*)(outf + (size_t)node * 128 + l * 8)     = o0;
            *(float4*)(outf + (size_t)node * 128 + l * 8 + 4) = o1;
        }
    }
}

// ================= launch =================

extern "C" void kernel_launch(void* const* d_in, const int* in_sizes, int n_in,
                              void* d_out, int out_size, void* d_ws, size_t ws_size,
                              hipStream_t stream) {
    const float* x   = (const float*)d_in[0];
    const int*   ei  = (const int*)d_in[1];
    const float* W1  = (const float*)d_in[2];
    const float* b1  = (const float*)d_in[3];
    const float* Wmu = (const float*)d_in[4];
    const float* bmu = (const float*)d_in[5];
    const float* Wlv = (const float*)d_in[6];
    const float* blv = (const float*)d_in[7];
    float* out = (float*)d_out;

    const int n = in_sizes[0] / 128;   // 50000
    const int E = in_sizes[1] / 2;     // 800000
    const int* src = ei;
    const int* dst = ei + E;

    char* ws = (char*)d_ws;
    float* dis    = (float*)(ws + 0x00000);
    int*   count  = (int*)  (ws + 0x40000);
    int*   rowptr = (int*)  (ws + 0x80000);
    int*   cursor = (int*)  (ws + 0xC0000);
    int*   excl   = (int*)  (ws + 0x100000);
    int*   bsum   = (int*)  (ws + 0x140000);
    int*   col    = (int*)  (ws + 0x180000);            // E ints (3.2MB)
    uint4* h1b    = (uint4*)(ws + 0x580000);            // n*128 bf16 (12.8MB)
    uint4* r1b    = (uint4*)(ws + 0x1200000);           // n*128 bf16 (12.8MB)
    float* agg2   = (float*)(ws + 0x1E40000);           // n*128 f32  (25.6MB)

    const int gN    = (n + THREADS - 1) / THREADS;
    const int gE    = (E + THREADS - 1) / THREADS;
    const int gAgg  = (n + 3) / 4;
    const int gGemm = (n + 63) / 64;
    const int nb    = (n + 255) / 256;

    // CSR build + degrees
    k_zero<<<gN, THREADS, 0, stream>>>(count, n);
    k_hist<<<gE, THREADS, 0, stream>>>(dst, count, E);
    k_dis <<<gN, THREADS, 0, stream>>>(count, dis, n);
    k_scan_local<<<nb, 256, 0, stream>>>(count, excl, bsum, n);
    k_scan_bsum <<<1, 256, 0, stream>>>(bsum, nb);
    k_scan_add  <<<gN, THREADS, 0, stream>>>(excl, bsum, rowptr, cursor, n, E);
    k_fill<<<gE, THREADS, 0, stream>>>(src, dst, cursor, col, E);

    // h1b = bf16(x @ W1)
    k_gemm128_rt<<<gGemm, THREADS, 0, stream>>>(x, W1, h1b, n);

    // r1b = bf16(relu(b1 + A_norm @ h1))
    k_agg_bf16<false><<<gAgg, THREADS, 0, stream>>>(h1b, rowptr, col, dis, b1, r1b, nullptr, n);

    // agg2 = A_norm @ r1   (f32)
    k_agg_bf16<true><<<gAgg, THREADS, 0, stream>>>(r1b, rowptr, col, dis, nullptr, nullptr, agg2, n);

    // [mu | logvar] = agg2 @ [Wmu|Wlv] + bias
    k_gemm_out_rt<<<gGemm, THREADS, 0, stream>>>(agg2, Wmu, Wlv, bmu, blv, out, n);
}

// Round 6
// 239.047 us; speedup vs baseline: 12.4882x; 1.0734x over previous
//
#include <hip/hip_runtime.h>
#include <hip/hip_bf16.h>

#define THREADS 256

// ---------- bf16 pack/unpack helpers ----------
__device__ __forceinline__ unsigned pack2(float a, float b) {
    __hip_bfloat16 ba = __float2bfloat16(a);
    __hip_bfloat16 bb = __float2bfloat16(b);
    unsigned short ua, ub;
    __builtin_memcpy(&ua, &ba, 2);
    __builtin_memcpy(&ub, &bb, 2);
    return ((unsigned)ub << 16) | ua;
}
__device__ __forceinline__ float unpack_lo(unsigned u) { return __uint_as_float(u << 16); }
__device__ __forceinline__ float unpack_hi(unsigned u) { return __uint_as_float(u & 0xffff0000u); }

// ================= CSR build =================

__global__ void k_zero(int* __restrict__ p, int n) {
    int i = blockIdx.x * blockDim.x + threadIdx.x;
    if (i < n) p[i] = 0;
}

__global__ void k_hist(const int* __restrict__ dst, int* __restrict__ count, int E) {
    int i = blockIdx.x * blockDim.x + threadIdx.x;
    if (i < E) atomicAdd(&count[dst[i]], 1);
}

__global__ void k_dis(const int* __restrict__ count, float* __restrict__ dis, int n) {
    int i = blockIdx.x * blockDim.x + threadIdx.x;
    if (i < n) dis[i] = rsqrtf((float)(count[i] + 1));
}

__global__ __launch_bounds__(256) void k_scan_local(const int* __restrict__ count,
                                                    int* __restrict__ excl,
                                                    int* __restrict__ bsum, int n) {
    __shared__ int tile[256];
    int i = blockIdx.x * 256 + threadIdx.x;
    int v = (i < n) ? count[i] : 0;
    tile[threadIdx.x] = v;
    __syncthreads();
    for (int off = 1; off < 256; off <<= 1) {
        int add = (threadIdx.x >= off) ? tile[threadIdx.x - off] : 0;
        __syncthreads();
        tile[threadIdx.x] += add;
        __syncthreads();
    }
    if (i < n) excl[i] = tile[threadIdx.x] - v;
    if (threadIdx.x == 255) bsum[blockIdx.x] = tile[255];
}

__global__ __launch_bounds__(256) void k_scan_bsum(int* __restrict__ bsum, int nb) {
    __shared__ int tile[256];
    int v = (threadIdx.x < nb) ? bsum[threadIdx.x] : 0;
    tile[threadIdx.x] = v;
    __syncthreads();
    for (int off = 1; off < 256; off <<= 1) {
        int add = (threadIdx.x >= off) ? tile[threadIdx.x - off] : 0;
        __syncthreads();
        tile[threadIdx.x] += add;
        __syncthreads();
    }
    if (threadIdx.x < nb) bsum[threadIdx.x] = tile[threadIdx.x] - v;
}

__global__ void k_scan_add(const int* __restrict__ excl, const int* __restrict__ bsum,
                           int* __restrict__ rowptr, int* __restrict__ cursor,
                           int n, int E) {
    int i = blockIdx.x * blockDim.x + threadIdx.x;
    if (i < n) {
        int v = excl[i] + bsum[i >> 8];
        rowptr[i] = v;
        cursor[i] = v;
    }
    if (i == 0) rowptr[n] = E;
}

__global__ void k_fill(const int* __restrict__ src, const int* __restrict__ dst,
                       int* __restrict__ cursor, int* __restrict__ col, int E) {
    int e = blockIdx.x * blockDim.x + threadIdx.x;
    if (e >= E) return;
    int pos = atomicAdd(&cursor[dst[e]], 1);
    col[pos] = src[e];
}

// ====== register-tiled GEMM, 64x64 block (32KB LDS, conflict-free) ==========
// hb[n,128](bf16) = A[n,128] @ W[128,128].  Grid = rowBlocks*2; blockIdx&1
// selects the 64-col half.  Thread tile 4 rows x 4 cols (16 cg x 16 rg).

__global__ __launch_bounds__(256) void k_gemm128_rt(const float* __restrict__ A,
                                                    const float* __restrict__ W,
                                                    unsigned* __restrict__ outb, int n) {
    __shared__ float Wl[128 * 64];
    const int ch = blockIdx.x & 1;
    const int rowBlk = blockIdx.x >> 1;

    for (int idx = threadIdx.x * 4; idx < 128 * 64; idx += 256 * 4) {
        int k = idx >> 6, j = idx & 63;
        *(float4*)&Wl[idx] = *(const float4*)&W[k * 128 + ch * 64 + j];
    }
    __syncthreads();

    const int cg = threadIdx.x & 15;
    const int rg = threadIdx.x >> 4;
    const int r0 = rowBlk * 64 + rg * 4;

    int ri[4];
#pragma unroll
    for (int r = 0; r < 4; ++r) { int i = r0 + r; ri[r] = (i < n) ? i : (n - 1); }

    float acc[4][4];
#pragma unroll
    for (int r = 0; r < 4; ++r)
#pragma unroll
        for (int c = 0; c < 4; ++c) acc[r][c] = 0.f;

#pragma unroll 4
    for (int k4 = 0; k4 < 32; ++k4) {
        float4 a[4];
#pragma unroll
        for (int r = 0; r < 4; ++r)
            a[r] = *(const float4*)(A + (size_t)ri[r] * 128 + k4 * 4);
#pragma unroll
        for (int kk = 0; kk < 4; ++kk) {
            float4 w = *(const float4*)&Wl[(k4 * 4 + kk) * 64 + cg * 4];
#pragma unroll
            for (int r = 0; r < 4; ++r) {
                float av = (kk == 0) ? a[r].x : (kk == 1) ? a[r].y : (kk == 2) ? a[r].z : a[r].w;
                acc[r][0] += av * w.x; acc[r][1] += av * w.y;
                acc[r][2] += av * w.z; acc[r][3] += av * w.w;
            }
        }
    }

#pragma unroll
    for (int r = 0; r < 4; ++r) {
        int i = r0 + r;
        if (i >= n) continue;
        uint2 o;
        o.x = pack2(acc[r][0], acc[r][1]);
        o.y = pack2(acc[r][2], acc[r][3]);
        *(uint2*)&outb[(size_t)i * 64 + ch * 32 + cg * 2] = o;
    }
}

// == final GEMM 64x64 block: ch=0 -> mu (Wmu), ch=1 -> logvar (Wlv), f32 out ==

__global__ __launch_bounds__(256) void k_gemm_out_rt(const float* __restrict__ A,
                                                     const float* __restrict__ Wmu,
                                                     const float* __restrict__ Wlv,
                                                     const float* __restrict__ bmu,
                                                     const float* __restrict__ blv,
                                                     float* __restrict__ out, int n) {
    __shared__ float Wl[128 * 64];
    const int ch = blockIdx.x & 1;
    const int rowBlk = blockIdx.x >> 1;
    const float* Wsrc = ch ? Wlv : Wmu;          // [128,64] contiguous
    const float* bsrc = ch ? blv : bmu;

    for (int idx = threadIdx.x * 4; idx < 128 * 64; idx += 256 * 4)
        *(float4*)&Wl[idx] = *(const float4*)&Wsrc[idx];
    __syncthreads();

    const int cg = threadIdx.x & 15;
    const int rg = threadIdx.x >> 4;
    const int r0 = rowBlk * 64 + rg * 4;

    float4 bb = *(const float4*)&bsrc[cg * 4];

    int ri[4];
#pragma unroll
    for (int r = 0; r < 4; ++r) { int i = r0 + r; ri[r] = (i < n) ? i : (n - 1); }

    float acc[4][4];
#pragma unroll
    for (int r = 0; r < 4; ++r) {
        acc[r][0] = bb.x; acc[r][1] = bb.y; acc[r][2] = bb.z; acc[r][3] = bb.w;
    }

#pragma unroll 4
    for (int k4 = 0; k4 < 32; ++k4) {
        float4 a[4];
#pragma unroll
        for (int r = 0; r < 4; ++r)
            a[r] = *(const float4*)(A + (size_t)ri[r] * 128 + k4 * 4);
#pragma unroll
        for (int kk = 0; kk < 4; ++kk) {
            float4 w = *(const float4*)&Wl[(k4 * 4 + kk) * 64 + cg * 4];
#pragma unroll
            for (int r = 0; r < 4; ++r) {
                float av = (kk == 0) ? a[r].x : (kk == 1) ? a[r].y : (kk == 2) ? a[r].z : a[r].w;
                acc[r][0] += av * w.x; acc[r][1] += av * w.y;
                acc[r][2] += av * w.z; acc[r][3] += av * w.w;
            }
        }
    }

    float* dstp = out + (size_t)ch * n * 64;     // mu block then logvar block
#pragma unroll
    for (int r = 0; r < 4; ++r) {
        int i = r0 + r;
        if (i >= n) continue;
        float4 o = {acc[r][0], acc[r][1], acc[r][2], acc[r][3]};
        *(float4*)(dstp + (size_t)i * 64 + cg * 4) = o;
    }
}

// ================= bf16 gather-aggregate =================
// One 64-lane wave per node, quarter-wave (16 lanes x 16B) per edge:
// 4 edges in flight + 1-deep prefetch. Combine quarters via shfl_xor(16,32).

template <bool PASS2>
__global__ __launch_bounds__(256) void k_agg_bf16(const uint4* __restrict__ hb,
                                                  const int* __restrict__ rowptr,
                                                  const int* __restrict__ col,
                                                  const float* __restrict__ dis,
                                                  const float* __restrict__ bias,
                                                  uint4* __restrict__ outb,
                                                  float* __restrict__ outf, int n) {
    int node = blockIdx.x * 4 + (threadIdx.x >> 6);
    if (node >= n) return;
    int lane = threadIdx.x & 63;
    int q = lane >> 4, l = lane & 15;
    float di = dis[node];

    float acc[8];
#pragma unroll
    for (int c = 0; c < 8; ++c) acc[c] = 0.f;

    int end = rowptr[node + 1];
    int k = rowptr[node] + q;

    int s0 = (k < end) ? col[k] : -1;
    uint4 v0 = {0, 0, 0, 0};
    float w0 = 0.f;
    if (s0 >= 0) { v0 = hb[(size_t)s0 * 16 + l]; w0 = dis[s0] * di; }

    while (k < end) {
        int k1 = k + 4;
        int s1 = (k1 < end) ? col[k1] : -1;
        uint4 v1 = {0, 0, 0, 0};
        float w1 = 0.f;
        if (s1 >= 0) { v1 = hb[(size_t)s1 * 16 + l]; w1 = dis[s1] * di; }

        acc[0] += unpack_lo(v0.x) * w0; acc[1] += unpack_hi(v0.x) * w0;
        acc[2] += unpack_lo(v0.y) * w0; acc[3] += unpack_hi(v0.y) * w0;
        acc[4] += unpack_lo(v0.z) * w0; acc[5] += unpack_hi(v0.z) * w0;
        acc[6] += unpack_lo(v0.w) * w0; acc[7] += unpack_hi(v0.w) * w0;

        k = k1; s0 = s1; v0 = v1; w0 = w1;
    }

#pragma unroll
    for (int c = 0; c < 8; ++c) acc[c] += __shfl_xor(acc[c], 16);
#pragma unroll
    for (int c = 0; c < 8; ++c) acc[c] += __shfl_xor(acc[c], 32);

    if (q == 0) {
        uint4 sv = hb[(size_t)node * 16 + l];
        float d2 = di * di;
        float self[8];
        self[0] = unpack_lo(sv.x); self[1] = unpack_hi(sv.x);
        self[2] = unpack_lo(sv.y); self[3] = unpack_hi(sv.y);
        self[4] = unpack_lo(sv.z); self[5] = unpack_hi(sv.z);
        self[6] = unpack_lo(sv.w); self[7] = unpack_hi(sv.w);
        if (!PASS2) {
            float4 b0 = *(const float4*)(bias + l * 8);
            float4 b1 = *(const float4*)(bias + l * 8 + 4);
            float bv[8] = {b0.x, b0.y, b0.z, b0.w, b1.x, b1.y, b1.z, b1.w};
#pragma unroll
            for (int c = 0; c < 8; ++c)
                acc[c] = fmaxf(acc[c] + self[c] * d2 + bv[c], 0.f);
            uint4 o;
            o.x = pack2(acc[0], acc[1]);
            o.y = pack2(acc[2], acc[3]);
            o.z = pack2(acc[4], acc[5]);
            o.w = pack2(acc[6], acc[7]);
            outb[(size_t)node * 16 + l] = o;
        } else {
#pragma unroll
            for (int c = 0; c < 8; ++c) acc[c] += self[c] * d2;
            float4 o0 = {acc[0], acc[1], acc[2], acc[3]};
            float4 o1 = {acc[4], acc[5], acc[6], acc[7]};
            *(float4*)(outf + (size_t)node * 128 + l * 8)     = o0;
            *(float4*)(outf + (size_t)node * 128 + l * 8 + 4) = o1;
        }
    }
}

// ================= launch =================

extern "C" void kernel_launch(void* const* d_in, const int* in_sizes, int n_in,
                              void* d_out, int out_size, void* d_ws, size_t ws_size,
                              hipStream_t stream) {
    const float* x   = (const float*)d_in[0];
    const int*   ei  = (const int*)d_in[1];
    const float* W1  = (const float*)d_in[2];
    const float* b1  = (const float*)d_in[3];
    const float* Wmu = (const float*)d_in[4];
    const float* bmu = (const float*)d_in[5];
    const float* Wlv = (const float*)d_in[6];
    const float* blv = (const float*)d_in[7];
    float* out = (float*)d_out;

    const int n = in_sizes[0] / 128;   // 50000
    const int E = in_sizes[1] / 2;     // 800000
    const int* src = ei;
    const int* dst = ei + E;

    char* ws = (char*)d_ws;
    float* dis    = (float*)(ws + 0x00000);
    int*   count  = (int*)  (ws + 0x40000);
    int*   rowptr = (int*)  (ws + 0x80000);
    int*   cursor = (int*)  (ws + 0xC0000);
    int*   excl   = (int*)  (ws + 0x100000);
    int*   bsum   = (int*)  (ws + 0x140000);
    int*   col    = (int*)  (ws + 0x180000);            // E ints (3.2MB)
    uint4* h1b    = (uint4*)(ws + 0x580000);            // n*128 bf16 (12.8MB)
    uint4* r1b    = (uint4*)(ws + 0x1200000);           // n*128 bf16 (12.8MB)
    float* agg2   = (float*)(ws + 0x1E40000);           // n*128 f32  (25.6MB)

    const int gN    = (n + THREADS - 1) / THREADS;
    const int gE    = (E + THREADS - 1) / THREADS;
    const int gAgg  = (n + 3) / 4;
    const int gGemm = ((n + 63) / 64) * 2;              // 64-row x 64-col blocks
    const int nb    = (n + 255) / 256;

    // CSR build + degrees
    k_zero<<<gN, THREADS, 0, stream>>>(count, n);
    k_hist<<<gE, THREADS, 0, stream>>>(dst, count, E);
    k_dis <<<gN, THREADS, 0, stream>>>(count, dis, n);
    k_scan_local<<<nb, 256, 0, stream>>>(count, excl, bsum, n);
    k_scan_bsum <<<1, 256, 0, stream>>>(bsum, nb);
    k_scan_add  <<<gN, THREADS, 0, stream>>>(excl, bsum, rowptr, cursor, n, E);
    k_fill<<<gE, THREADS, 0, stream>>>(src, dst, cursor, col, E);

    // h1b = bf16(x @ W1)
    k_gemm128_rt<<<gGemm, THREADS, 0, stream>>>(x, W1, (unsigned*)h1b, n);

    // r1b = bf16(relu(b1 + A_norm @ h1))
    k_agg_bf16<false><<<gAgg, THREADS, 0, stream>>>(h1b, rowptr, col, dis, b1, r1b, nullptr, n);

    // agg2 = A_norm @ r1   (f32)
    k_agg_bf16<true><<<gAgg, THREADS, 0, stream>>>(r1b, rowptr, col, dis, nullptr, nullptr, agg2, n);

    // [mu | logvar] = agg2 @ [Wmu|Wlv] + bias
    k_gemm_out_rt<<<gGemm, THREADS, 0, stream>>>(agg2, Wmu, Wlv, bmu, blv, out, n);
}

// Round 7
// 196.125 us; speedup vs baseline: 15.2213x; 1.2189x over previous
//
#include <hip/hip_runtime.h>
#include <hip/hip_bf16.h>

#define THREADS 256

typedef _Float16 half8 __attribute__((ext_vector_type(8)));
typedef float f32x4 __attribute__((ext_vector_type(4)));

// ---------- bf16 pack/unpack helpers ----------
__device__ __forceinline__ unsigned pack2(float a, float b) {
    __hip_bfloat16 ba = __float2bfloat16(a);
    __hip_bfloat16 bb = __float2bfloat16(b);
    unsigned short ua, ub;
    __builtin_memcpy(&ua, &ba, 2);
    __builtin_memcpy(&ub, &bb, 2);
    return ((unsigned)ub << 16) | ua;
}
__device__ __forceinline__ unsigned short bf16u(float a) {
    __hip_bfloat16 ba = __float2bfloat16(a);
    unsigned short ua;
    __builtin_memcpy(&ua, &ba, 2);
    return ua;
}
__device__ __forceinline__ float unpack_lo(unsigned u) { return __uint_as_float(u << 16); }
__device__ __forceinline__ float unpack_hi(unsigned u) { return __uint_as_float(u & 0xffff0000u); }

// ================= CSR build =================

__global__ void k_zero(int* __restrict__ p, int n) {
    int i = blockIdx.x * blockDim.x + threadIdx.x;
    if (i < n) p[i] = 0;
}

__global__ void k_hist(const int* __restrict__ dst, int* __restrict__ count, int E) {
    int i = blockIdx.x * blockDim.x + threadIdx.x;
    if (i < E) atomicAdd(&count[dst[i]], 1);
}

__global__ void k_dis(const int* __restrict__ count, float* __restrict__ dis, int n) {
    int i = blockIdx.x * blockDim.x + threadIdx.x;
    if (i < n) dis[i] = rsqrtf((float)(count[i] + 1));
}

__global__ __launch_bounds__(256) void k_scan_local(const int* __restrict__ count,
                                                    int* __restrict__ excl,
                                                    int* __restrict__ bsum, int n) {
    __shared__ int tile[256];
    int i = blockIdx.x * 256 + threadIdx.x;
    int v = (i < n) ? count[i] : 0;
    tile[threadIdx.x] = v;
    __syncthreads();
    for (int off = 1; off < 256; off <<= 1) {
        int add = (threadIdx.x >= off) ? tile[threadIdx.x - off] : 0;
        __syncthreads();
        tile[threadIdx.x] += add;
        __syncthreads();
    }
    if (i < n) excl[i] = tile[threadIdx.x] - v;
    if (threadIdx.x == 255) bsum[blockIdx.x] = tile[255];
}

__global__ __launch_bounds__(256) void k_scan_bsum(int* __restrict__ bsum, int nb) {
    __shared__ int tile[256];
    int v = (threadIdx.x < nb) ? bsum[threadIdx.x] : 0;
    tile[threadIdx.x] = v;
    __syncthreads();
    for (int off = 1; off < 256; off <<= 1) {
        int add = (threadIdx.x >= off) ? tile[threadIdx.x - off] : 0;
        __syncthreads();
        tile[threadIdx.x] += add;
        __syncthreads();
    }
    if (threadIdx.x < nb) bsum[threadIdx.x] = tile[threadIdx.x] - v;
}

__global__ void k_scan_add(const int* __restrict__ excl, const int* __restrict__ bsum,
                           int* __restrict__ rowptr, int* __restrict__ cursor,
                           int n, int E) {
    int i = blockIdx.x * blockDim.x + threadIdx.x;
    if (i < n) {
        int v = excl[i] + bsum[i >> 8];
        rowptr[i] = v;
        cursor[i] = v;
    }
    if (i == 0) rowptr[n] = E;
}

__global__ void k_fill(const int* __restrict__ src, const int* __restrict__ dst,
                       int* __restrict__ cursor, int* __restrict__ col, int E) {
    int e = blockIdx.x * blockDim.x + threadIdx.x;
    if (e >= E) return;
    int pos = atomicAdd(&cursor[dst[e]], 1);
    col[pos] = src[e];
}

// ================= MFMA GEMM (f16 in, f32 accum) =========================
// C[n,128] = A[n,128] @ W[128,128]. Block: 64 rows x 128 cols, 4 waves.
// Wave = 16 rows x 8 col-tiles of 16x16; K-loop 4 steps of 32.
// W staged in LDS in *fragment order*: one conflict-free ds_read_b128 per
// B-frag. Frag k-map (lane l, elem e): k = (l>>4)*4 + (e&3) + 16*(e>>2).
// A read from global (row = l&15), 2x dwordx4 + cvt per k-step.
// Out: packed bf16 [n][128].

__global__ __launch_bounds__(256) void k_gemm128_mfma(const float* __restrict__ A,
                                                      const float* __restrict__ W,
                                                      unsigned short* __restrict__ outb,
                                                      int n) {
    __shared__ _Float16 Wl[16384];   // 32KB, frag-order: slot=(c*4+s)*64+l
    for (int slot = threadIdx.x; slot < 2048; slot += 256) {
        int l = slot & 63;
        int cs = slot >> 6;
        int s = cs & 3, c = cs >> 2;
        int colw = c * 16 + (l & 15);
        int k0 = s * 32 + (l >> 4) * 4;
        const float* wp0 = W + (size_t)k0 * 128 + colw;
        const float* wp1 = wp0 + 16 * 128;
        half8 h;
        h[0] = (_Float16)wp0[0];   h[1] = (_Float16)wp0[128];
        h[2] = (_Float16)wp0[256]; h[3] = (_Float16)wp0[384];
        h[4] = (_Float16)wp1[0];   h[5] = (_Float16)wp1[128];
        h[6] = (_Float16)wp1[256]; h[7] = (_Float16)wp1[384];
        *(half8*)(Wl + (size_t)slot * 8) = h;
    }
    __syncthreads();

    const int l  = threadIdx.x & 63;
    const int wid = threadIdx.x >> 6;
    const int lm = l & 15, q = l >> 4;
    const int rowA = blockIdx.x * 64 + wid * 16 + lm;
    const int ra = (rowA < n) ? rowA : (n - 1);

    f32x4 acc[8];
#pragma unroll
    for (int c = 0; c < 8; ++c) acc[c] = (f32x4){0.f, 0.f, 0.f, 0.f};

#pragma unroll
    for (int s = 0; s < 4; ++s) {
        const float* ap = A + (size_t)ra * 128 + s * 32 + q * 4;
        float4 a0 = *(const float4*)ap;
        float4 a1 = *(const float4*)(ap + 16);
        half8 af;
        af[0] = (_Float16)a0.x; af[1] = (_Float16)a0.y;
        af[2] = (_Float16)a0.z; af[3] = (_Float16)a0.w;
        af[4] = (_Float16)a1.x; af[5] = (_Float16)a1.y;
        af[6] = (_Float16)a1.z; af[7] = (_Float16)a1.w;
#pragma unroll
        for (int c = 0; c < 8; ++c) {
            half8 bf = *(half8*)(Wl + ((size_t)((c * 4 + s) * 64 + l)) * 8);
            acc[c] = __builtin_amdgcn_mfma_f32_16x16x32_f16(af, bf, acc[c], 0, 0, 0);
        }
    }

    const int gr0 = blockIdx.x * 64 + wid * 16 + q * 4;
#pragma unroll
    for (int r = 0; r < 4; ++r) {
        int gr = gr0 + r;
        if (gr >= n) continue;
#pragma unroll
        for (int c = 0; c < 8; ++c)
            outb[(size_t)gr * 128 + c * 16 + lm] = bf16u(acc[c][r]);
    }
}

// ==== MFMA final GEMM: cols 0-63 = Wmu -> mu, cols 64-127 = Wlv -> logvar ===

__global__ __launch_bounds__(256) void k_gemm_out_mfma(const float* __restrict__ A,
                                                       const float* __restrict__ Wmu,
                                                       const float* __restrict__ Wlv,
                                                       const float* __restrict__ bmu,
                                                       const float* __restrict__ blv,
                                                       float* __restrict__ out, int n) {
    __shared__ _Float16 Wl[16384];
    for (int slot = threadIdx.x; slot < 2048; slot += 256) {
        int l = slot & 63;
        int cs = slot >> 6;
        int s = cs & 3, c = cs >> 2;
        int colw = c * 16 + (l & 15);
        const float* Wsrc = (colw < 64) ? Wmu : Wlv;
        int cj = colw & 63;
        int k0 = s * 32 + (l >> 4) * 4;
        const float* wp0 = Wsrc + (size_t)k0 * 64 + cj;
        const float* wp1 = wp0 + 16 * 64;
        half8 h;
        h[0] = (_Float16)wp0[0];   h[1] = (_Float16)wp0[64];
        h[2] = (_Float16)wp0[128]; h[3] = (_Float16)wp0[192];
        h[4] = (_Float16)wp1[0];   h[5] = (_Float16)wp1[64];
        h[6] = (_Float16)wp1[128]; h[7] = (_Float16)wp1[192];
        *(half8*)(Wl + (size_t)slot * 8) = h;
    }
    __syncthreads();

    const int l  = threadIdx.x & 63;
    const int wid = threadIdx.x >> 6;
    const int lm = l & 15, q = l >> 4;
    const int rowA = blockIdx.x * 64 + wid * 16 + lm;
    const int ra = (rowA < n) ? rowA : (n - 1);

    f32x4 acc[8];
#pragma unroll
    for (int c = 0; c < 8; ++c) {
        int colw = c * 16 + lm;
        float bv = (colw < 64) ? bmu[colw] : blv[colw - 64];
        acc[c] = (f32x4){bv, bv, bv, bv};
    }

#pragma unroll
    for (int s = 0; s < 4; ++s) {
        const float* ap = A + (size_t)ra * 128 + s * 32 + q * 4;
        float4 a0 = *(const float4*)ap;
        float4 a1 = *(const float4*)(ap + 16);
        half8 af;
        af[0] = (_Float16)a0.x; af[1] = (_Float16)a0.y;
        af[2] = (_Float16)a0.z; af[3] = (_Float16)a0.w;
        af[4] = (_Float16)a1.x; af[5] = (_Float16)a1.y;
        af[6] = (_Float16)a1.z; af[7] = (_Float16)a1.w;
#pragma unroll
        for (int c = 0; c < 8; ++c) {
            half8 bf = *(half8*)(Wl + ((size_t)((c * 4 + s) * 64 + l)) * 8);
            acc[c] = __builtin_amdgcn_mfma_f32_16x16x32_f16(af, bf, acc[c], 0, 0, 0);
        }
    }

    float* lvp = out + (size_t)n * 64;
    const int gr0 = blockIdx.x * 64 + wid * 16 + q * 4;
#pragma unroll
    for (int r = 0; r < 4; ++r) {
        int gr = gr0 + r;
        if (gr >= n) continue;
#pragma unroll
        for (int c = 0; c < 8; ++c) {
            int colw = c * 16 + lm;
            float v = acc[c][r];
            if (colw < 64) out[(size_t)gr * 64 + colw] = v;
            else           lvp[(size_t)gr * 64 + (colw - 64)] = v;
        }
    }
}

// ================= bf16 gather-aggregate =================
// One 64-lane wave per node, quarter-wave (16 lanes x 16B) per edge:
// 4 edges in flight + 1-deep prefetch. Combine quarters via shfl_xor(16,32).

template <bool PASS2>
__global__ __launch_bounds__(256) void k_agg_bf16(const uint4* __restrict__ hb,
                                                  const int* __restrict__ rowptr,
                                                  const int* __restrict__ col,
                                                  const float* __restrict__ dis,
                                                  const float* __restrict__ bias,
                                                  uint4* __restrict__ outb,
                                                  float* __restrict__ outf, int n) {
    int node = blockIdx.x * 4 + (threadIdx.x >> 6);
    if (node >= n) return;
    int lane = threadIdx.x & 63;
    int q = lane >> 4, l = lane & 15;
    float di = dis[node];

    float acc[8];
#pragma unroll
    for (int c = 0; c < 8; ++c) acc[c] = 0.f;

    int end = rowptr[node + 1];
    int k = rowptr[node] + q;

    int s0 = (k < end) ? col[k] : -1;
    uint4 v0 = {0, 0, 0, 0};
    float w0 = 0.f;
    if (s0 >= 0) { v0 = hb[(size_t)s0 * 16 + l]; w0 = dis[s0] * di; }

    while (k < end) {
        int k1 = k + 4;
        int s1 = (k1 < end) ? col[k1] : -1;
        uint4 v1 = {0, 0, 0, 0};
        float w1 = 0.f;
        if (s1 >= 0) { v1 = hb[(size_t)s1 * 16 + l]; w1 = dis[s1] * di; }

        acc[0] += unpack_lo(v0.x) * w0; acc[1] += unpack_hi(v0.x) * w0;
        acc[2] += unpack_lo(v0.y) * w0; acc[3] += unpack_hi(v0.y) * w0;
        acc[4] += unpack_lo(v0.z) * w0; acc[5] += unpack_hi(v0.z) * w0;
        acc[6] += unpack_lo(v0.w) * w0; acc[7] += unpack_hi(v0.w) * w0;

        k = k1; s0 = s1; v0 = v1; w0 = w1;
    }

#pragma unroll
    for (int c = 0; c < 8; ++c) acc[c] += __shfl_xor(acc[c], 16);
#pragma unroll
    for (int c = 0; c < 8; ++c) acc[c] += __shfl_xor(acc[c], 32);

    if (q == 0) {
        uint4 sv = hb[(size_t)node * 16 + l];
        float d2 = di * di;
        float self[8];
        self[0] = unpack_lo(sv.x); self[1] = unpack_hi(sv.x);
        self[2] = unpack_lo(sv.y); self[3] = unpack_hi(sv.y);
        self[4] = unpack_lo(sv.z); self[5] = unpack_hi(sv.z);
        self[6] = unpack_lo(sv.w); self[7] = unpack_hi(sv.w);
        if (!PASS2) {
            float4 b0 = *(const float4*)(bias + l * 8);
            float4 b1 = *(const float4*)(bias + l * 8 + 4);
            float bv[8] = {b0.x, b0.y, b0.z, b0.w, b1.x, b1.y, b1.z, b1.w};
#pragma unroll
            for (int c = 0; c < 8; ++c)
                acc[c] = fmaxf(acc[c] + self[c] * d2 + bv[c], 0.f);
            uint4 o;
            o.x = pack2(acc[0], acc[1]);
            o.y = pack2(acc[2], acc[3]);
            o.z = pack2(acc[4], acc[5]);
            o.w = pack2(acc[6], acc[7]);
            outb[(size_t)node * 16 + l] = o;
        } else {
#pragma unroll
            for (int c = 0; c < 8; ++c) acc[c] += self[c] * d2;
            float4 o0 = {acc[0], acc[1], acc[2], acc[3]};
            float4 o1 = {acc[4], acc[5], acc[6], acc[7]};
            *(float4*)(outf + (size_t)node * 128 + l * 8)     = o0;
            *(float4*)(outf + (size_t)node * 128 + l * 8 + 4) = o1;
        }
    }
}

// ================= launch =================

extern "C" void kernel_launch(void* const* d_in, const int* in_sizes, int n_in,
                              void* d_out, int out_size, void* d_ws, size_t ws_size,
                              hipStream_t stream) {
    const float* x   = (const float*)d_in[0];
    const int*   ei  = (const int*)d_in[1];
    const float* W1  = (const float*)d_in[2];
    const float* b1  = (const float*)d_in[3];
    const float* Wmu = (const float*)d_in[4];
    const float* bmu = (const float*)d_in[5];
    const float* Wlv = (const float*)d_in[6];
    const float* blv = (const float*)d_in[7];
    float* out = (float*)d_out;

    const int n = in_sizes[0] / 128;   // 50000
    const int E = in_sizes[1] / 2;     // 800000
    const int* src = ei;
    const int* dst = ei + E;

    char* ws = (char*)d_ws;
    float* dis    = (float*)(ws + 0x00000);
    int*   count  = (int*)  (ws + 0x40000);
    int*   rowptr = (int*)  (ws + 0x80000);
    int*   cursor = (int*)  (ws + 0xC0000);
    int*   excl   = (int*)  (ws + 0x100000);
    int*   bsum   = (int*)  (ws + 0x140000);
    int*   col    = (int*)  (ws + 0x180000);            // E ints (3.2MB)
    uint4* h1b    = (uint4*)(ws + 0x580000);            // n*128 bf16 (12.8MB)
    uint4* r1b    = (uint4*)(ws + 0x1200000);           // n*128 bf16 (12.8MB)
    float* agg2   = (float*)(ws + 0x1E40000);           // n*128 f32  (25.6MB)

    const int gN    = (n + THREADS - 1) / THREADS;
    const int gE    = (E + THREADS - 1) / THREADS;
    const int gAgg  = (n + 3) / 4;
    const int gGemm = (n + 63) / 64;
    const int nb    = (n + 255) / 256;

    // CSR build + degrees
    k_zero<<<gN, THREADS, 0, stream>>>(count, n);
    k_hist<<<gE, THREADS, 0, stream>>>(dst, count, E);
    k_dis <<<gN, THREADS, 0, stream>>>(count, dis, n);
    k_scan_local<<<nb, 256, 0, stream>>>(count, excl, bsum, n);
    k_scan_bsum <<<1, 256, 0, stream>>>(bsum, nb);
    k_scan_add  <<<gN, THREADS, 0, stream>>>(excl, bsum, rowptr, cursor, n, E);
    k_fill<<<gE, THREADS, 0, stream>>>(src, dst, cursor, col, E);

    // h1b = bf16(x @ W1)   (f16 MFMA)
    k_gemm128_mfma<<<gGemm, THREADS, 0, stream>>>(x, W1, (unsigned short*)h1b, n);

    // r1b = bf16(relu(b1 + A_norm @ h1))
    k_agg_bf16<false><<<gAgg, THREADS, 0, stream>>>(h1b, rowptr, col, dis, b1, r1b, nullptr, n);

    // agg2 = A_norm @ r1   (f32)
    k_agg_bf16<true><<<gAgg, THREADS, 0, stream>>>(r1b, rowptr, col, dis, nullptr, nullptr, agg2, n);

    // [mu | logvar] = agg2 @ [Wmu|Wlv] + bias   (f16 MFMA)
    k_gemm_out_mfma<<<gGemm, THREADS, 0, stream>>>(agg2, Wmu, Wlv, bmu, blv, out, n);
}